// Round 1
// baseline (2836.150 us; speedup 1.0000x reference)
//
#include <hip/hip_runtime.h>
#include <hip/hip_bf16.h>

#define VOCAB 50000
#define EMB   300
#define FILT  400
#define ATT   200
#define KW    3
#define BB    4096
#define NN    30

// LDS budget: keep static shared < 64 KB/block.
// Wl chunk: ECH e-rows at a time, padded pitch 36 floats (144 B, 16B-aligned,
// stride-36 writes are only 4-way bank aliased and the gather is tiny).
#define ECH      100
#define WL_PITCH 36

// Computes relu(conv(W,conv_w)+conv_b) for one batch item into Cl[NN][FILT].
// Wl is the staging buffer for ECH embedding rows at a time.
// Column m of Wl corresponds to padded input row m-1 (m=0 and m=NN+1 are the
// zero padding), so C[n] = sum_k Wcol[n+k]*w[k].
__device__ __forceinline__ void compute_C_block(
    int b, int tid,
    const int* __restrict__ idx, const float* __restrict__ emb,
    const float* __restrict__ conv_w, const float* __restrict__ conv_b,
    float (*Wl)[WL_PITCH], float (*Cl)[FILT])
{
    float acc[NN];
    float bias = (tid < FILT) ? conv_b[tid] : 0.f;
#pragma unroll
    for (int n = 0; n < NN; n++) acc[n] = bias;

    const float* wrow = conv_w + (size_t)tid * (EMB * KW);

    for (int e0 = 0; e0 < EMB; e0 += ECH) {
        // stage chunk: zero pad columns, gather embedding rows
        for (int e = tid; e < ECH; e += 512) { Wl[e][0] = 0.f; Wl[e][NN + 1] = 0.f; }
        for (int i = tid; i < NN * ECH; i += 512) {
            int n = i / ECH;
            int e = i - n * ECH;
            int row = idx[b * NN + n];
            Wl[e][n + 1] = emb[(size_t)row * EMB + e0 + e];
        }
        __syncthreads();

        if (tid < FILT) {
            for (int e = 0; e < ECH; e++) {
                // 32 window values, lane-uniform LDS broadcast via float4
                float wreg[32];
                const float4* src = (const float4*)(&Wl[e][0]);
#pragma unroll
                for (int j = 0; j < 8; j++) {
                    float4 t4 = src[j];
                    wreg[4 * j + 0] = t4.x; wreg[4 * j + 1] = t4.y;
                    wreg[4 * j + 2] = t4.z; wreg[4 * j + 3] = t4.w;
                }
                float cw0 = wrow[(e0 + e) * 3 + 0];
                float cw1 = wrow[(e0 + e) * 3 + 1];
                float cw2 = wrow[(e0 + e) * 3 + 2];
#pragma unroll
                for (int n = 0; n < NN; n++)
                    acc[n] = fmaf(wreg[n], cw0,
                             fmaf(wreg[n + 1], cw1,
                             fmaf(wreg[n + 2], cw2, acc[n])));
            }
        }
        __syncthreads();  // before next chunk overwrites Wl
    }

    if (tid < FILT) {
#pragma unroll
        for (int n = 0; n < NN; n++) Cl[n][tid] = fmaxf(acc[n], 0.f);
    }
    __syncthreads();
}

__global__ __launch_bounds__(512) void k1_conv_att(
    const int* __restrict__ idx, const float* __restrict__ emb,
    const float* __restrict__ conv_w, const float* __restrict__ conv_b,
    const float* __restrict__ v, const float* __restrict__ vb,
    const float* __restrict__ q,
    float* __restrict__ a_out, __hip_bfloat16* __restrict__ C_out, int storeC)
{
    __shared__ float Wl[ECH][WL_PITCH];   // 14.4 KB
    __shared__ float Cl[NN][FILT];        // 48.0 KB
    __shared__ float aacc[NN];
    int b = blockIdx.x;
    int tid = threadIdx.x;

    if (tid < NN) aacc[tid] = 0.f;
    compute_C_block(b, tid, idx, emb, conv_w, conv_b, Wl, Cl);

    if (storeC) {
        const float* Cf = (const float*)Cl;
        for (int i = tid; i < NN * FILT; i += 512)
            C_out[(size_t)b * (NN * FILT) + i] = __float2bfloat16(Cf[i]);
    }

    // a[n] = sum_att tanh(Cl[n,:]·v[:,att] + vb[att]) * q[att]
    for (int p = tid; p < NN * ATT; p += 512) {
        int n = p / ATT;
        int att = p - n * ATT;
        float s = vb[att];
        const float* vcol = v + att;
        for (int f = 0; f < FILT; f++)
            s = fmaf(Cl[n][f], vcol[(size_t)f * ATT], s);
        float t = tanhf(s);
        atomicAdd(&aacc[n], t * q[att]);
    }
    __syncthreads();
    if (tid < NN) a_out[b * NN + tid] = aacc[tid];
}

// softmax over batch dim per position n, then mask
__global__ __launch_bounds__(256) void k2_softmax(
    const float* __restrict__ a, const int* __restrict__ idx,
    float* __restrict__ alpha)
{
    int n = blockIdx.x;
    int tid = threadIdx.x;
    constexpr int PER = BB / 256;  // 16
    float vals[PER];
    float m = -1e30f;
#pragma unroll
    for (int i = 0; i < PER; i++) {
        int b = i * 256 + tid;
        vals[i] = a[b * NN + n];
        m = fmaxf(m, vals[i]);
    }
    __shared__ float red[8];
#pragma unroll
    for (int off = 32; off >= 1; off >>= 1) m = fmaxf(m, __shfl_xor(m, off, 64));
    int wave = tid >> 6;
    if ((tid & 63) == 0) red[wave] = m;
    __syncthreads();
    m = fmaxf(fmaxf(red[0], red[1]), fmaxf(red[2], red[3]));

    float s = 0.f;
#pragma unroll
    for (int i = 0; i < PER; i++) {
        vals[i] = expf(vals[i] - m);
        s += vals[i];
    }
#pragma unroll
    for (int off = 32; off >= 1; off >>= 1) s += __shfl_xor(s, off, 64);
    if ((tid & 63) == 0) red[4 + wave] = s;
    __syncthreads();
    s = red[4] + red[5] + red[6] + red[7];
    float inv = 1.f / s;
#pragma unroll
    for (int i = 0; i < PER; i++) {
        int b = i * 256 + tid;
        float msk = (idx[b * NN + n] != 0) ? 1.f : 0.f;
        alpha[b * NN + n] = vals[i] * inv * msk;
    }
}

__global__ __launch_bounds__(512) void k3_pool(
    const float* __restrict__ alpha, const __hip_bfloat16* __restrict__ C,
    float* __restrict__ out)
{
    int b = blockIdx.x;
    int tid = threadIdx.x;
    __shared__ float al[NN];
    if (tid < NN) al[tid] = alpha[b * NN + tid];
    __syncthreads();
    if (tid < FILT) {
        const __hip_bfloat16* Cb = C + (size_t)b * (NN * FILT) + tid;
        float s = 0.f;
#pragma unroll
        for (int n = 0; n < NN; n++)
            s = fmaf(al[n], __bfloat162float(Cb[(size_t)n * FILT]), s);
        out[b * FILT + tid] = s;
    }
}

// fallback if workspace is too small to hold bf16 C: recompute conv
__global__ __launch_bounds__(512) void k3_pool_rc(
    const int* __restrict__ idx, const float* __restrict__ emb,
    const float* __restrict__ conv_w, const float* __restrict__ conv_b,
    const float* __restrict__ alpha, float* __restrict__ out)
{
    __shared__ float Wl[ECH][WL_PITCH];
    __shared__ float Cl[NN][FILT];
    __shared__ float al[NN];
    int b = blockIdx.x;
    int tid = threadIdx.x;
    if (tid < NN) al[tid] = alpha[b * NN + tid];
    compute_C_block(b, tid, idx, emb, conv_w, conv_b, Wl, Cl);
    if (tid < FILT) {
        float s = 0.f;
#pragma unroll
        for (int n = 0; n < NN; n++)
            s = fmaf(al[n], Cl[n][tid], s);
        out[b * FILT + tid] = s;
    }
}

extern "C" void kernel_launch(void* const* d_in, const int* in_sizes, int n_in,
                              void* d_out, int out_size, void* d_ws, size_t ws_size,
                              hipStream_t stream) {
    const int*   idx    = (const int*)d_in[0];
    const float* emb    = (const float*)d_in[1];
    const float* conv_w = (const float*)d_in[2];
    const float* conv_b = (const float*)d_in[3];
    const float* v      = (const float*)d_in[4];
    const float* vb     = (const float*)d_in[5];
    const float* q      = (const float*)d_in[6];
    float* out = (float*)d_out;

    char* ws = (char*)d_ws;
    float* a_buf     = (float*)ws;                              // B*N fp32
    float* alpha_buf = (float*)(ws + (size_t)BB * NN * 4);      // B*N fp32
    __hip_bfloat16* C_buf = (__hip_bfloat16*)(ws + (size_t)2 * BB * NN * 4);
    size_t need = (size_t)2 * BB * NN * 4 + (size_t)BB * NN * FILT * 2;
    int storeC = (ws_size >= need) ? 1 : 0;

    k1_conv_att<<<BB, 512, 0, stream>>>(idx, emb, conv_w, conv_b, v, vb, q,
                                        a_buf, C_buf, storeC);
    k2_softmax<<<NN, 256, 0, stream>>>(a_buf, idx, alpha_buf);
    if (storeC)
        k3_pool<<<BB, 512, 0, stream>>>(alpha_buf, C_buf, out);
    else
        k3_pool_rc<<<BB, 512, 0, stream>>>(idx, emb, conv_w, conv_b, alpha_buf, out);
}

// Round 2
// 535.151 us; speedup vs baseline: 5.2997x; 5.2997x over previous
//
#include <hip/hip_runtime.h>
#include <hip/hip_bf16.h>

#define VOCAB 50000
#define EMB   300
#define FILT  400
#define ATT   200
#define BB    4096
#define NN    30

#define EMB_STRIDE 304   // bf16 elems per padded emb row (608 B, 16B-mult)
#define ATTP  208        // att padded to 13 n-tiles
#define KC    416        // padded K for attention GEMM (13 K-steps of 32)

// guide-verified (m93/m97): bf16 MFMA fragments as short8
typedef short bf16x8 __attribute__((ext_vector_type(8)));
typedef float f32x4  __attribute__((ext_vector_type(4)));

static __device__ __forceinline__ unsigned short f2bf(float f) {
    __hip_bfloat16 h = __float2bfloat16(f);
    union { __hip_bfloat16 h; unsigned short u; } c; c.h = h; return c.u;
}

// ---------------- prep kernels ----------------

// emb fp32 [VOCAB][300] -> bf16 [VOCAB+1][EMB_STRIDE], row VOCAB = zeros (conv pad row)
__global__ __launch_bounds__(256) void kP_emb(const float* __restrict__ emb,
                                              unsigned short* __restrict__ embb) {
    long t = (long)blockIdx.x * 256 + threadIdx.x;          // pairs
    long npairs = (long)(VOCAB + 1) * (EMB_STRIDE / 2);
    if (t >= npairs) return;
    int row = (int)(t / (EMB_STRIDE / 2));
    int e = (int)(t % (EMB_STRIDE / 2)) * 2;
    float f0 = 0.f, f1 = 0.f;
    if (row < VOCAB) {
        if (e < EMB)     f0 = emb[(long)row * EMB + e];
        if (e + 1 < EMB) f1 = emb[(long)row * EMB + e + 1];
    }
    ushort2 u; u.x = f2bf(f0); u.y = f2bf(f1);
    *(ushort2*)(embb + (long)row * EMB_STRIDE + e) = u;
}

// conv_w [400][300][3] -> Bconv[k][f][e] bf16 [3][400][320], e>=300 zero
__global__ __launch_bounds__(256) void kP_bconv(const float* __restrict__ conv_w,
                                                unsigned short* __restrict__ Bc) {
    int t = blockIdx.x * 256 + threadIdx.x;
    if (t >= 3 * FILT * 320) return;
    int k = t / (FILT * 320);
    int rem = t - k * (FILT * 320);
    int f = rem / 320;
    int e = rem - f * 320;
    float val = (e < EMB) ? conv_w[((size_t)f * EMB + e) * 3 + k] : 0.f;
    Bc[t] = f2bf(val);
}

// v [400][200] -> Bv[att][f] bf16 [208][416] zero-padded; also vbp/qp fp32 [208]
__global__ __launch_bounds__(256) void kP_bv(const float* __restrict__ v,
                                             const float* __restrict__ vb,
                                             const float* __restrict__ q,
                                             unsigned short* __restrict__ Bv,
                                             float* __restrict__ vbp,
                                             float* __restrict__ qp) {
    int t = blockIdx.x * 256 + threadIdx.x;
    if (t < ATTP * KC) {
        int att = t / KC;
        int f = t - att * KC;
        float val = (att < ATT && f < FILT) ? v[(size_t)f * ATT + att] : 0.f;
        Bv[t] = f2bf(val);
    }
    if (t < ATTP) {
        vbp[t] = (t < ATT) ? vb[t] : 0.f;
        qp[t]  = (t < ATT) ? q[t] : 0.f;
    }
}

// ---------------- k1: conv GEMM (no LDS, no barriers) ----------------
// C[row=b*32+n padded][f] = relu(bias + sum_k sum_e emb[tok(n+k-1)][e]*cw_k[e][f])
// block: 320 thr = 5 waves; block tile 64 rows x 400 f; wave tile 64x80 (4x5 MFMA tiles)
// MODE: 2 = bf16 emb table + Bconv; 1 = fp32 emb gather + Bconv; 0 = fp32 emb + raw conv_w
template<int MODE>
__global__ __launch_bounds__(320) void k1_conv(
    const int* __restrict__ idx,
    const float* __restrict__ emb,
    const unsigned short* __restrict__ embb,
    const unsigned short* __restrict__ Bc,
    const float* __restrict__ conv_w,
    const float* __restrict__ conv_b,
    unsigned short* __restrict__ Cws)
{
    const int lane = threadIdx.x & 63;
    const int wave = threadIdx.x >> 6;     // 0..4
    const int lm = lane & 15;
    const int qq = lane >> 4;
    const int row0 = blockIdx.x * 64;
    const int f0 = wave * 80;

    int tok[4][3];
    bool inv[4][3];
#pragma unroll
    for (int mt = 0; mt < 4; mt++) {
        int gr = row0 + mt * 16 + lm;
        int b = gr >> 5, n = gr & 31;
#pragma unroll
        for (int k = 0; k < 3; k++) {
            int np = n + k - 1;
            bool ok = (np >= 0 && np < NN);
            inv[mt][k] = !ok;
            tok[mt][k] = ok ? idx[b * NN + np] : (MODE == 2 ? VOCAB : 0);
        }
    }

    f32x4 acc[4][5];
#pragma unroll
    for (int mt = 0; mt < 4; mt++)
#pragma unroll
        for (int nt = 0; nt < 5; nt++)
            acc[mt][nt] = (f32x4){0.f, 0.f, 0.f, 0.f};

#pragma unroll 2
    for (int e0 = 0; e0 < 320; e0 += 32) {
#pragma unroll
        for (int k = 0; k < 3; k++) {
            bf16x8 aF[4];
#pragma unroll
            for (int mt = 0; mt < 4; mt++) {
                if (MODE == 2) {
                    aF[mt] = *(const bf16x8*)(embb + tok[mt][k] * EMB_STRIDE + e0 + 8 * qq);
                } else {
                    union { bf16x8 v; unsigned short u[8]; } u;
#pragma unroll
                    for (int j = 0; j < 8; j++) {
                        int e = e0 + 8 * qq + j;
                        float f = (!inv[mt][k] && e < EMB) ? emb[(long)tok[mt][k] * EMB + e] : 0.f;
                        u.u[j] = f2bf(f);
                    }
                    aF[mt] = u.v;
                }
            }
            bf16x8 bF[5];
#pragma unroll
            for (int nt = 0; nt < 5; nt++) {
                int f = f0 + nt * 16 + lm;
                if (MODE >= 1) {
                    bF[nt] = *(const bf16x8*)(Bc + (k * FILT + f) * 320 + e0 + 8 * qq);
                } else {
                    union { bf16x8 v; unsigned short u[8]; } u;
#pragma unroll
                    for (int j = 0; j < 8; j++) {
                        int e = e0 + 8 * qq + j;
                        float val = (e < EMB) ? conv_w[((size_t)f * EMB + e) * 3 + k] : 0.f;
                        u.u[j] = f2bf(val);
                    }
                    bF[nt] = u.v;
                }
            }
#pragma unroll
            for (int nt = 0; nt < 5; nt++)
#pragma unroll
                for (int mt = 0; mt < 4; mt++)
                    acc[mt][nt] = __builtin_amdgcn_mfma_f32_16x16x32_bf16(
                        aF[mt], bF[nt], acc[mt][nt], 0, 0, 0);
        }
    }

    float cb[5];
#pragma unroll
    for (int nt = 0; nt < 5; nt++) cb[nt] = conv_b[f0 + nt * 16 + lm];

#pragma unroll
    for (int mt = 0; mt < 4; mt++) {
#pragma unroll
        for (int r = 0; r < 4; r++) {
            int gr = row0 + mt * 16 + qq * 4 + r;
            int b = gr >> 5, n = gr & 31;
            if (n < NN) {
                int orow = b * NN + n;
#pragma unroll
                for (int nt = 0; nt < 5; nt++) {
                    float vv = acc[mt][nt][r] + cb[nt];
                    vv = fmaxf(vv, 0.f);
                    Cws[(size_t)orow * FILT + f0 + nt * 16 + lm] = f2bf(vv);
                }
            }
        }
    }
}

// ---------------- k2: attention logits GEMM ----------------
// a[row] = sum_att tanh( C[row,:]@v[:,att] + vb[att] ) * q[att]
// block: 256 thr = 4 waves, each wave one 16-row m-tile x 13 att-tiles
__global__ __launch_bounds__(256) void k2_att(
    const unsigned short* __restrict__ Cws,
    const unsigned short* __restrict__ Bv,
    const float* __restrict__ vbp, const float* __restrict__ qp,
    float* __restrict__ a_out)
{
    const int lane = threadIdx.x & 63;
    const int wave = threadIdx.x >> 6;
    const int lm = lane & 15, qq = lane >> 4;
    const int r0 = blockIdx.x * 64 + wave * 16;

    f32x4 acc[13];
#pragma unroll
    for (int nt = 0; nt < 13; nt++) acc[nt] = (f32x4){0.f, 0.f, 0.f, 0.f};

#pragma unroll 2
    for (int ks = 0; ks < 13; ks++) {
        // A cols >=400 read into next row's data; B rows there are zero => harmless
        bf16x8 aF = *(const bf16x8*)(Cws + (size_t)(r0 + lm) * FILT + ks * 32 + 8 * qq);
#pragma unroll
        for (int nt = 0; nt < 13; nt++) {
            bf16x8 bF = *(const bf16x8*)(Bv + (nt * 16 + lm) * KC + ks * 32 + 8 * qq);
            acc[nt] = __builtin_amdgcn_mfma_f32_16x16x32_bf16(aF, bF, acc[nt], 0, 0, 0);
        }
    }

    float rs[4] = {0.f, 0.f, 0.f, 0.f};
#pragma unroll
    for (int nt = 0; nt < 13; nt++) {
        int att = nt * 16 + lm;
        float vbv = vbp[att], qv = qp[att];
#pragma unroll
        for (int r = 0; r < 4; r++)
            rs[r] += tanhf(acc[nt][r] + vbv) * qv;   // padded att: acc=0,q=0 -> 0
    }
#pragma unroll
    for (int off = 1; off < 16; off <<= 1)
#pragma unroll
        for (int r = 0; r < 4; r++) rs[r] += __shfl_xor(rs[r], off, 64);
    if (lm == 0) {
#pragma unroll
        for (int r = 0; r < 4; r++) a_out[r0 + qq * 4 + r] = rs[r];
    }
}

// ---------------- k3: softmax over batch dim (in-place a -> alpha) ----------------
__global__ __launch_bounds__(256) void k3_softmax(float* __restrict__ a,
                                                  const int* __restrict__ idx) {
    int n = blockIdx.x;
    int tid = threadIdx.x;
    constexpr int PER = BB / 256;  // 16
    float vals[PER];
    float m = -1e30f;
#pragma unroll
    for (int i = 0; i < PER; i++) {
        int b = i * 256 + tid;
        vals[i] = a[b * NN + n];
        m = fmaxf(m, vals[i]);
    }
    __shared__ float red[8];
#pragma unroll
    for (int off = 32; off >= 1; off >>= 1) m = fmaxf(m, __shfl_xor(m, off, 64));
    int wave = tid >> 6;
    if ((tid & 63) == 0) red[wave] = m;
    __syncthreads();
    m = fmaxf(fmaxf(red[0], red[1]), fmaxf(red[2], red[3]));

    float s = 0.f;
#pragma unroll
    for (int i = 0; i < PER; i++) {
        vals[i] = expf(vals[i] - m);
        s += vals[i];
    }
#pragma unroll
    for (int off = 32; off >= 1; off >>= 1) s += __shfl_xor(s, off, 64);
    if ((tid & 63) == 0) red[4 + wave] = s;
    __syncthreads();
    s = red[4] + red[5] + red[6] + red[7];
    float inv = 1.f / s;
#pragma unroll
    for (int i = 0; i < PER; i++) {
        int b = i * 256 + tid;
        float msk = (idx[b * NN + n] != 0) ? 1.f : 0.f;
        a[b * NN + n] = vals[i] * inv * msk;
    }
}

// ---------------- k4: weighted pooling ----------------
__global__ __launch_bounds__(512) void k4_pool(
    const float* __restrict__ alpha, const unsigned short* __restrict__ C,
    float* __restrict__ out)
{
    int b = blockIdx.x;
    int tid = threadIdx.x;
    __shared__ float al[NN];
    if (tid < NN) al[tid] = alpha[b * NN + tid];
    __syncthreads();
    if (tid < FILT) {
        const unsigned short* Cb = C + (size_t)b * (NN * FILT) + tid;
        float s = 0.f;
#pragma unroll
        for (int n = 0; n < NN; n++) {
            union { unsigned int u; float f; } c; c.u = ((unsigned int)Cb[(size_t)n * FILT]) << 16;
            s = fmaf(al[n], c.f, s);
        }
        out[b * FILT + tid] = s;
    }
}

extern "C" void kernel_launch(void* const* d_in, const int* in_sizes, int n_in,
                              void* d_out, int out_size, void* d_ws, size_t ws_size,
                              hipStream_t stream) {
    const int*   idx    = (const int*)d_in[0];
    const float* emb    = (const float*)d_in[1];
    const float* conv_w = (const float*)d_in[2];
    const float* conv_b = (const float*)d_in[3];
    const float* v      = (const float*)d_in[4];
    const float* vb     = (const float*)d_in[5];
    const float* q      = (const float*)d_in[6];
    float* out = (float*)d_out;

    char* ws = (char*)d_ws;
    // layout (all modes): a/alpha | Bv | vbp | qp | Cws [| Bconv [| embb]]
    size_t o = 0;
    float* a_buf = (float*)(ws + o);               o += (size_t)BB * NN * 4;      // 491520
    unsigned short* Bv = (unsigned short*)(ws + o); o += (size_t)ATTP * KC * 2;   // 173056
    float* vbp = (float*)(ws + o);                 o += 1024;
    float* qp  = (float*)(ws + o);                 o += 1024;
    o = (o + 255) & ~(size_t)255;
    unsigned short* Cws = (unsigned short*)(ws + o);
    o += (size_t)BB * NN * FILT * 2 + 256;         // 98,304,000 + slack
    size_t need0 = o;
    unsigned short* Bc = (unsigned short*)(ws + o);
    o += (size_t)3 * FILT * 320 * 2;               // 768,000
    size_t need1 = o;
    unsigned short* embb = (unsigned short*)(ws + o);
    o += (size_t)(VOCAB + 1) * EMB_STRIDE * 2 + 128;
    size_t need2 = o;

    int mode = (ws_size >= need2) ? 2 : (ws_size >= need1) ? 1 : 0;
    (void)need0;

    // prep
    kP_bv<<<(ATTP * KC + 255) / 256, 256, 0, stream>>>(v, vb, q, Bv, vbp, qp);
    if (mode >= 1)
        kP_bconv<<<(3 * FILT * 320 + 255) / 256, 256, 0, stream>>>(conv_w, Bc);
    if (mode == 2) {
        long npairs = (long)(VOCAB + 1) * (EMB_STRIDE / 2);
        kP_emb<<<(int)((npairs + 255) / 256), 256, 0, stream>>>(emb, embb);
    }

    // main chain
    if (mode == 2)
        k1_conv<2><<<BB / 2, 320, 0, stream>>>(idx, emb, embb, Bc, conv_w, conv_b, Cws);
    else if (mode == 1)
        k1_conv<1><<<BB / 2, 320, 0, stream>>>(idx, emb, embb, Bc, conv_w, conv_b, Cws);
    else
        k1_conv<0><<<BB / 2, 320, 0, stream>>>(idx, emb, embb, Bc, conv_w, conv_b, Cws);

    k2_att<<<(BB * NN) / 64, 256, 0, stream>>>(Cws, Bv, vbp, qp, a_buf);
    k3_softmax<<<NN, 256, 0, stream>>>(a_buf, idx);
    k4_pool<<<BB, 512, 0, stream>>>(a_buf, Cws, out);
}

// Round 4
// 495.874 us; speedup vs baseline: 5.7195x; 1.0792x over previous
//
#include <hip/hip_runtime.h>
#include <hip/hip_bf16.h>

#define VOCAB 50000
#define EMB   300
#define FILT  400
#define ATT   200
#define BB    4096
#define NN    30

#define ATTP  208        // att padded to 13 n-tiles
#define KC    416        // padded K for attention GEMM (13 K-steps of 32)
#define AST   328        // LDS A-stage row stride (ushorts): 656 B = 164 dw == 4 (mod 32) -> 2-way free

typedef short bf16x8 __attribute__((ext_vector_type(8)));
typedef float f32x4  __attribute__((ext_vector_type(4)));
typedef unsigned short u16x4 __attribute__((ext_vector_type(4)));

static __device__ __forceinline__ unsigned short f2bf(float f) {
    __hip_bfloat16 h = __float2bfloat16(f);
    union { __hip_bfloat16 h; unsigned short u; } c; c.h = h; return c.u;
}
static __device__ __forceinline__ float bf2f(unsigned short u) {
    union { unsigned int u; float f; } c; c.u = ((unsigned int)u) << 16; return c.f;
}

// ---------------- prep: Bc [3][400][320], Bv [208][416], vbp/qp [208] ----------------
__global__ __launch_bounds__(256) void kP(const float* __restrict__ conv_w,
                                          const float* __restrict__ v,
                                          const float* __restrict__ vb,
                                          const float* __restrict__ q,
                                          unsigned short* __restrict__ Bc,
                                          unsigned short* __restrict__ Bv,
                                          float* __restrict__ vbp,
                                          float* __restrict__ qp) {
    int t = blockIdx.x * 256 + threadIdx.x;
    const int NBC = 3 * FILT * 320;
    if (t < NBC) {
        int k = t / (FILT * 320);
        int rem = t - k * (FILT * 320);
        int f = rem / 320;
        int e = rem - f * 320;
        float val = (e < EMB) ? conv_w[((size_t)f * EMB + e) * 3 + k] : 0.f;
        Bc[t] = f2bf(val);
    } else {
        int t2 = t - NBC;
        if (t2 < ATTP * KC) {
            int att = t2 / KC;
            int fcol = t2 - att * KC;
            float val = (att < ATT && fcol < FILT) ? v[(size_t)fcol * ATT + att] : 0.f;
            Bv[t2] = f2bf(val);
        }
    }
    if (t < ATTP) {
        vbp[t] = (t < ATT) ? vb[t] : 0.f;
        qp[t]  = (t < ATT) ? q[t] : 0.f;
    }
}

// ---------------- k1: conv GEMM with LDS-staged A (single-purpose LDS, one barrier) ----------------
// block = 320 thr (5 waves), 2 batches (64 GEMM rows: b*32+n, n in [0,32), n>=30 pad).
// LDS row j holds padded input row (j&31): 0 = left pad, 1..30 = tokens, 31 = right pad.
// C row gr needs LDS rows gr..gr+2 (rows 64,65 zeroed; only discarded rows read them).
__global__ __launch_bounds__(320) void k1_conv(
    const int* __restrict__ idx,
    const float* __restrict__ emb,
    const unsigned short* __restrict__ Bc,
    const float* __restrict__ conv_b,
    unsigned short* __restrict__ Cws)
{
    __shared__ unsigned short As[66 * AST];   // 43,296 B
    const int bid = blockIdx.x;
    const int t = threadIdx.x;

    // ---- phase 1: stage A (fp32 emb gather -> bf16 LDS) ----
    {
        int j = t / 5, c = t - (t / 5) * 5;       // row 0..63, chunk 0..4 (64 elems each)
        int b = j >> 5, j2 = j & 31;
        int tok = -1;
        if (j2 >= 1 && j2 <= 30) tok = idx[(bid * 2 + b) * NN + (j2 - 1)];
#pragma unroll
        for (int i = 0; i < 8; i++) {
            int e = c * 64 + i * 8;
            bf16x8 val = (bf16x8){0, 0, 0, 0, 0, 0, 0, 0};
            if (tok >= 0 && e < 304) {
                float f[8];
                if (e <= 292) {
                    float4 x = *(const float4*)(emb + (size_t)tok * EMB + e);
                    float4 y = *(const float4*)(emb + (size_t)tok * EMB + e + 4);
                    f[0] = x.x; f[1] = x.y; f[2] = x.z; f[3] = x.w;
                    f[4] = y.x; f[5] = y.y; f[6] = y.z; f[7] = y.w;
                } else {
#pragma unroll
                    for (int jj = 0; jj < 8; jj++) {
                        int ee = e + jj;
                        f[jj] = (ee < EMB) ? emb[(size_t)tok * EMB + ee] : 0.f;
                    }
                }
#pragma unroll
                for (int jj = 0; jj < 8; jj++) val[jj] = (short)f2bf(f[jj]);
            }
            *(bf16x8*)(As + j * AST + e) = val;
        }
        if (t < 82) *(bf16x8*)(As + 64 * AST + t * 8) = (bf16x8){0, 0, 0, 0, 0, 0, 0, 0};
    }
    __syncthreads();

    const int lane = t & 63;
    const int wave = t >> 6;          // 0..4
    const int lm = lane & 15;
    const int qq = lane >> 4;
    const int f0 = wave * 80;

    // ---- phase 2: conv GEMM (A from LDS, B from L2) ----
    f32x4 acc[4][5];
#pragma unroll
    for (int mt = 0; mt < 4; mt++)
#pragma unroll
        for (int nt = 0; nt < 5; nt++)
            acc[mt][nt] = (f32x4){0.f, 0.f, 0.f, 0.f};

    for (int e0 = 0; e0 < 320; e0 += 32) {
#pragma unroll
        for (int k = 0; k < 3; k++) {
            bf16x8 aF[4];
#pragma unroll
            for (int mt = 0; mt < 4; mt++)
                aF[mt] = *(const bf16x8*)(As + (mt * 16 + lm + k) * AST + e0 + 8 * qq);
#pragma unroll
            for (int nt = 0; nt < 5; nt++) {
                bf16x8 bF = *(const bf16x8*)(Bc + ((size_t)(k * FILT + f0 + nt * 16 + lm)) * 320 + e0 + 8 * qq);
#pragma unroll
                for (int mt = 0; mt < 4; mt++)
                    acc[mt][nt] = __builtin_amdgcn_mfma_f32_16x16x32_bf16(aF[mt], bF, acc[mt][nt], 0, 0, 0);
            }
        }
    }

    // ---- epilogue: bias + relu -> global Cws (bf16) ----
    float cb[5];
#pragma unroll
    for (int nt = 0; nt < 5; nt++) cb[nt] = conv_b[f0 + nt * 16 + lm];
#pragma unroll
    for (int mt = 0; mt < 4; mt++) {
#pragma unroll
        for (int r = 0; r < 4; r++) {
            int lrow = mt * 16 + qq * 4 + r;
            int n = lrow & 31;
            int bglob = bid * 2 + (lrow >> 5);
            if (n < NN) {
#pragma unroll
                for (int nt = 0; nt < 5; nt++) {
                    float vv = fmaxf(acc[mt][nt][r] + cb[nt], 0.f);
                    Cws[((size_t)bglob * NN + n) * FILT + f0 + nt * 16 + lm] = f2bf(vv);
                }
            }
        }
    }
}

// ---------------- k2: attention logits GEMM (R2-verbatim, post-timing-proven) ----------------
__global__ __launch_bounds__(256) void k2_att(
    const unsigned short* __restrict__ Cws,
    const unsigned short* __restrict__ Bv,
    const float* __restrict__ vbp, const float* __restrict__ qp,
    float* __restrict__ a_out)
{
    const int lane = threadIdx.x & 63;
    const int wave = threadIdx.x >> 6;
    const int lm = lane & 15, qq = lane >> 4;
    const int r0 = blockIdx.x * 64 + wave * 16;

    f32x4 acc[13];
#pragma unroll
    for (int nt = 0; nt < 13; nt++) acc[nt] = (f32x4){0.f, 0.f, 0.f, 0.f};

#pragma unroll 2
    for (int ks = 0; ks < 13; ks++) {
        // A cols >=400 read into next row's data; B rows there are zero => harmless
        bf16x8 aF = *(const bf16x8*)(Cws + (size_t)(r0 + lm) * FILT + ks * 32 + 8 * qq);
#pragma unroll
        for (int nt = 0; nt < 13; nt++) {
            bf16x8 bF = *(const bf16x8*)(Bv + (size_t)(nt * 16 + lm) * KC + ks * 32 + 8 * qq);
            acc[nt] = __builtin_amdgcn_mfma_f32_16x16x32_bf16(aF, bF, acc[nt], 0, 0, 0);
        }
    }

    float rs[4] = {0.f, 0.f, 0.f, 0.f};
#pragma unroll
    for (int nt = 0; nt < 13; nt++) {
        int att = nt * 16 + lm;
        float vbv = vbp[att], qv = qp[att];
#pragma unroll
        for (int r = 0; r < 4; r++)
            rs[r] += tanhf(acc[nt][r] + vbv) * qv;   // padded att: acc=0,q=0 -> 0
    }
#pragma unroll
    for (int off = 1; off < 16; off <<= 1)
#pragma unroll
        for (int r = 0; r < 4; r++) rs[r] += __shfl_xor(rs[r], off, 64);
    if (lm == 0) {
#pragma unroll
        for (int r = 0; r < 4; r++) a_out[r0 + qq * 4 + r] = rs[r];
    }
}

// ---------------- k3: softmax over batch dim (in-place a -> alpha) ----------------
__global__ __launch_bounds__(256) void k3_softmax(float* __restrict__ a,
                                                  const int* __restrict__ idx) {
    int n = blockIdx.x;
    int tid = threadIdx.x;
    constexpr int PER = BB / 256;  // 16
    float vals[PER];
    float m = -1e30f;
#pragma unroll
    for (int i = 0; i < PER; i++) {
        int b = i * 256 + tid;
        vals[i] = a[b * NN + n];
        m = fmaxf(m, vals[i]);
    }
    __shared__ float red[8];
#pragma unroll
    for (int off = 32; off >= 1; off >>= 1) m = fmaxf(m, __shfl_xor(m, off, 64));
    int wave = tid >> 6;
    if ((tid & 63) == 0) red[wave] = m;
    __syncthreads();
    m = fmaxf(fmaxf(red[0], red[1]), fmaxf(red[2], red[3]));

    float s = 0.f;
#pragma unroll
    for (int i = 0; i < PER; i++) {
        vals[i] = expf(vals[i] - m);
        s += vals[i];
    }
#pragma unroll
    for (int off = 32; off >= 1; off >>= 1) s += __shfl_xor(s, off, 64);
    if ((tid & 63) == 0) red[4 + wave] = s;
    __syncthreads();
    s = red[4] + red[5] + red[6] + red[7];
    float inv = 1.f / s;
#pragma unroll
    for (int i = 0; i < PER; i++) {
        int b = i * 256 + tid;
        float msk = (idx[b * NN + n] != 0) ? 1.f : 0.f;
        a[b * NN + n] = vals[i] * inv * msk;
    }
}

// ---------------- k4: weighted pooling, vectorized ----------------
__global__ __launch_bounds__(128) void k4_pool(
    const float* __restrict__ alpha, const unsigned short* __restrict__ C,
    float* __restrict__ out)
{
    int b = blockIdx.x;
    int tid = threadIdx.x;
    __shared__ float al[NN];
    if (tid < NN) al[tid] = alpha[b * NN + tid];
    __syncthreads();
    if (tid < 100) {
        int f = tid * 4;
        float s0 = 0.f, s1 = 0.f, s2 = 0.f, s3 = 0.f;
        const unsigned short* Cb = C + (size_t)b * (NN * FILT) + f;
#pragma unroll
        for (int n = 0; n < NN; n++) {
            u16x4 c = *(const u16x4*)(Cb + (size_t)n * FILT);
            float a = al[n];
            s0 = fmaf(a, bf2f(c[0]), s0);
            s1 = fmaf(a, bf2f(c[1]), s1);
            s2 = fmaf(a, bf2f(c[2]), s2);
            s3 = fmaf(a, bf2f(c[3]), s3);
        }
        float4 o; o.x = s0; o.y = s1; o.z = s2; o.w = s3;
        *(float4*)(out + (size_t)b * FILT + f) = o;
    }
}

extern "C" void kernel_launch(void* const* d_in, const int* in_sizes, int n_in,
                              void* d_out, int out_size, void* d_ws, size_t ws_size,
                              hipStream_t stream) {
    const int*   idx    = (const int*)d_in[0];
    const float* emb    = (const float*)d_in[1];
    const float* conv_w = (const float*)d_in[2];
    const float* conv_b = (const float*)d_in[3];
    const float* v      = (const float*)d_in[4];
    const float* vb     = (const float*)d_in[5];
    const float* q      = (const float*)d_in[6];
    float* out = (float*)d_out;

    // workspace layout (total 99,247,104 B <= 99,287,040 proven floor from R1):
    //   Bv [208][416] bf16 | vbp [256] f32 | qp [256] f32 | Bc [3][400][320] bf16 | Cws
    //   a_buf ALIASES Bc: k1 reads Bc before k2 writes a_buf (stream-ordered), and
    //   kP rewrites Bc every call, so no cross-call staleness.
    char* ws = (char*)d_ws;
    size_t o = 0;
    unsigned short* Bv = (unsigned short*)(ws + o);  o += (size_t)ATTP * KC * 2;      // 173,056
    float* vbp = (float*)(ws + o);                   o += 1024;
    float* qp  = (float*)(ws + o);                   o += 1024;                        // 175,104
    unsigned short* Bc = (unsigned short*)(ws + o);
    float* a_buf = (float*)(ws + o);                 // alias of Bc (491,520 <= 768,000)
    o += (size_t)3 * FILT * 320 * 2;                 // -> 943,104 (16B aligned)
    unsigned short* Cws = (unsigned short*)(ws + o);

    const int NP = 3 * FILT * 320 + ATTP * KC;
    kP<<<(NP + 255) / 256, 256, 0, stream>>>(conv_w, v, vb, q, Bc, Bv, vbp, qp);
    k1_conv<<<BB / 2, 320, 0, stream>>>(idx, emb, Bc, conv_b, Cws);
    k2_att<<<(BB * NN) / 64, 256, 0, stream>>>(Cws, Bv, vbp, qp, a_buf);
    k3_softmax<<<NN, 256, 0, stream>>>(a_buf, idx);
    k4_pool<<<BB, 128, 0, stream>>>(a_buf, Cws, out);
}

// Round 5
// 452.980 us; speedup vs baseline: 6.2611x; 1.0947x over previous
//
#include <hip/hip_runtime.h>
#include <hip/hip_bf16.h>

#define VOCAB 50000
#define EMB   300
#define FILT  400
#define ATT   200
#define BB    4096
#define NN    30

#define ATTP  208        // att padded to 13 n-tiles
#define KC    416        // padded K for attention GEMM (13 K-steps of 32)
#define AST   328        // LDS A-stage row stride (ushorts): 656 B = 164 dw == 4 (mod 32) -> 2-way free

typedef short bf16x8 __attribute__((ext_vector_type(8)));
typedef float f32x4  __attribute__((ext_vector_type(4)));
typedef unsigned short u16x4 __attribute__((ext_vector_type(4)));

static __device__ __forceinline__ unsigned short f2bf(float f) {
    __hip_bfloat16 h = __float2bfloat16(f);
    union { __hip_bfloat16 h; unsigned short u; } c; c.h = h; return c.u;
}
static __device__ __forceinline__ float bf2f(unsigned short u) {
    union { unsigned int u; float f; } c; c.u = ((unsigned int)u) << 16; return c.f;
}
// numerics validated in R3 first-pass (absmax 3.8e-6): x->+inf => e=inf => 1; x->-inf => e=0 => -1
static __device__ __forceinline__ float fast_tanh(float x) {
    float e = __expf(2.f * x);
    return 1.f - 2.f * __builtin_amdgcn_rcpf(e + 1.f);
}

// ---------------- prep: fragment-major Bc2 [750 tiles][512], Bv2 [169 tiles][512], vbp/qp ----------------
// Bc2 tile t=(k*10+es)*25+ft holds B[f=ft*16+lm][e=es*32+qq*8+j] at offset lm*32+qq*8+j
//   -> a wave's bF load (lane off = lm*32+qq*8, 16 B) reads 1 KB fully contiguous.
// Bv2 tile t=ks*13+at holds v[f=ks*32+qq*8+j][att=at*16+lm] at same offset.
__global__ __launch_bounds__(256) void kP(const float* __restrict__ conv_w,
                                          const float* __restrict__ v,
                                          const float* __restrict__ vb,
                                          const float* __restrict__ q,
                                          unsigned short* __restrict__ Bc2,
                                          unsigned short* __restrict__ Bv2,
                                          float* __restrict__ vbp,
                                          float* __restrict__ qp) {
    int t = blockIdx.x * 256 + threadIdx.x;
    const int NBC = 750 * 512;               // 384,000
    if (t < NBC) {
        int tau = t >> 9, off = t & 511;
        int lm = off >> 5, qq = (off >> 3) & 3, j = off & 7;
        int ft = tau % 25, es = (tau / 25) % 10, k = tau / 250;
        int f = ft * 16 + lm;
        int e = es * 32 + qq * 8 + j;
        float val = (e < EMB) ? conv_w[((size_t)f * EMB + e) * 3 + k] : 0.f;
        Bc2[t] = f2bf(val);
    } else {
        int t2 = t - NBC;
        if (t2 < 169 * 512) {                // 86,528
            int tau = t2 >> 9, off = t2 & 511;
            int lm = off >> 5, qq = (off >> 3) & 3, j = off & 7;
            int ks = tau / 13, at = tau % 13;
            int att = at * 16 + lm;
            int fcol = ks * 32 + qq * 8 + j;
            float val = (att < ATT && fcol < FILT) ? v[(size_t)fcol * ATT + att] : 0.f;
            Bv2[t2] = f2bf(val);
        }
    }
    if (t < ATTP) {
        vbp[t] = (t < ATT) ? vb[t] : 0.f;
        qp[t]  = (t < ATT) ? q[t] : 0.f;
    }
}

// ---------------- k1: conv GEMM, LDS-staged A, batched fragment-major B loads ----------------
// block = 320 thr (5 waves), 2 batches (64 rows), wave tile 64 x 80 (4 mt x 5 nt).
__global__ __launch_bounds__(320, 2) void k1_conv(
    const int* __restrict__ idx,
    const float* __restrict__ emb,
    const unsigned short* __restrict__ Bc2,
    const float* __restrict__ conv_b,
    unsigned short* __restrict__ Cws)
{
    __shared__ unsigned short As[66 * AST];   // 43,296 B
    const int bid = blockIdx.x;
    const int t = threadIdx.x;

    // ---- phase 1: stage A (fp32 emb gather -> bf16 LDS) — R4-proven ----
    {
        int j = t / 5, c = t - (t / 5) * 5;
        int b = j >> 5, j2 = j & 31;
        int tok = -1;
        if (j2 >= 1 && j2 <= 30) tok = idx[(bid * 2 + b) * NN + (j2 - 1)];
#pragma unroll
        for (int i = 0; i < 8; i++) {
            int e = c * 64 + i * 8;
            bf16x8 val = (bf16x8){0, 0, 0, 0, 0, 0, 0, 0};
            if (tok >= 0 && e < 304) {
                float f[8];
                if (e <= 292) {
                    float4 x = *(const float4*)(emb + (size_t)tok * EMB + e);
                    float4 y = *(const float4*)(emb + (size_t)tok * EMB + e + 4);
                    f[0] = x.x; f[1] = x.y; f[2] = x.z; f[3] = x.w;
                    f[4] = y.x; f[5] = y.y; f[6] = y.z; f[7] = y.w;
                } else {
#pragma unroll
                    for (int jj = 0; jj < 8; jj++) {
                        int ee = e + jj;
                        f[jj] = (ee < EMB) ? emb[(size_t)tok * EMB + ee] : 0.f;
                    }
                }
#pragma unroll
                for (int jj = 0; jj < 8; jj++) val[jj] = (short)f2bf(f[jj]);
            }
            *(bf16x8*)(As + j * AST + e) = val;
        }
        if (t < 82) *(bf16x8*)(As + 64 * AST + t * 8) = (bf16x8){0, 0, 0, 0, 0, 0, 0, 0};
    }
    __syncthreads();

    const int lane = t & 63;
    const int wave = t >> 6;
    const int lm = lane & 15;
    const int qq = lane >> 4;
    const int laneoff = lm * 32 + qq * 8;
    const int wave5 = wave * 5;

    f32x4 acc[4][5];
#pragma unroll
    for (int mt = 0; mt < 4; mt++)
#pragma unroll
        for (int nt = 0; nt < 5; nt++)
            acc[mt][nt] = (f32x4){0.f, 0.f, 0.f, 0.f};

#pragma unroll 2
    for (int es = 0; es < 10; es++) {
#pragma unroll
        for (int k = 0; k < 3; k++) {
            bf16x8 bF[5];
#pragma unroll
            for (int nt = 0; nt < 5; nt++)
                bF[nt] = *(const bf16x8*)(Bc2 + ((size_t)((k * 10 + es) * 25 + wave5 + nt)) * 512 + laneoff);
            bf16x8 aF[4];
#pragma unroll
            for (int mt = 0; mt < 4; mt++)
                aF[mt] = *(const bf16x8*)(As + (mt * 16 + lm + k) * AST + es * 32 + 8 * qq);
#pragma unroll
            for (int nt = 0; nt < 5; nt++)
#pragma unroll
                for (int mt = 0; mt < 4; mt++)
                    acc[mt][nt] = __builtin_amdgcn_mfma_f32_16x16x32_bf16(aF[mt], bF[nt], acc[mt][nt], 0, 0, 0);
        }
    }

    // ---- epilogue: bias + relu -> global Cws (bf16) ----
    const int f0 = wave * 80;
    float cb[5];
#pragma unroll
    for (int nt = 0; nt < 5; nt++) cb[nt] = conv_b[f0 + nt * 16 + lm];
#pragma unroll
    for (int mt = 0; mt < 4; mt++) {
#pragma unroll
        for (int r = 0; r < 4; r++) {
            int lrow = mt * 16 + qq * 4 + r;
            int n = lrow & 31;
            int bglob = bid * 2 + (lrow >> 5);
            if (n < NN) {
#pragma unroll
                for (int nt = 0; nt < 5; nt++) {
                    float vv = fmaxf(acc[mt][nt][r] + cb[nt], 0.f);
                    Cws[((size_t)bglob * NN + n) * FILT + f0 + nt * 16 + lm] = f2bf(vv);
                }
            }
        }
    }
}

// ---------------- k2: attention logits GEMM, batched B, wave tile 32 x 208 ----------------
// block = 256 thr (4 waves), M=128 rows/block, grid 960.
__global__ __launch_bounds__(256, 2) void k2_att(
    const unsigned short* __restrict__ Cws,
    const unsigned short* __restrict__ Bv2,
    const float* __restrict__ vbp, const float* __restrict__ qp,
    float* __restrict__ a_out)
{
    const int lane = threadIdx.x & 63;
    const int wave = threadIdx.x >> 6;
    const int lm = lane & 15, qq = lane >> 4;
    const int laneoff = lm * 32 + qq * 8;
    const int r0 = blockIdx.x * 128 + wave * 32;

    f32x4 acc[2][13];
#pragma unroll
    for (int mt = 0; mt < 2; mt++)
#pragma unroll
        for (int nt = 0; nt < 13; nt++) acc[mt][nt] = (f32x4){0.f, 0.f, 0.f, 0.f};

#pragma unroll 1
    for (int ks = 0; ks < 13; ks++) {
        bf16x8 bF[13];
#pragma unroll
        for (int nt = 0; nt < 13; nt++)
            bF[nt] = *(const bf16x8*)(Bv2 + ((size_t)(ks * 13 + nt)) * 512 + laneoff);
        bf16x8 aF[2];
#pragma unroll
        for (int mt = 0; mt < 2; mt++)   // cols >=400 overrun into next row; Bv2 rows there are 0
            aF[mt] = *(const bf16x8*)(Cws + (size_t)(r0 + mt * 16 + lm) * FILT + ks * 32 + 8 * qq);
#pragma unroll
        for (int nt = 0; nt < 13; nt++)
#pragma unroll
            for (int mt = 0; mt < 2; mt++)
                acc[mt][nt] = __builtin_amdgcn_mfma_f32_16x16x32_bf16(aF[mt], bF[nt], acc[mt][nt], 0, 0, 0);
    }

#pragma unroll
    for (int mt = 0; mt < 2; mt++) {
        float rs[4] = {0.f, 0.f, 0.f, 0.f};
#pragma unroll
        for (int nt = 0; nt < 13; nt++) {
            int att = nt * 16 + lm;
            float vbv = vbp[att], qv = qp[att];
#pragma unroll
            for (int r = 0; r < 4; r++)
                rs[r] += fast_tanh(acc[mt][nt][r] + vbv) * qv;   // padded att: acc=0,q=0 -> 0
        }
#pragma unroll
        for (int off = 1; off < 16; off <<= 1)
#pragma unroll
            for (int r = 0; r < 4; r++) rs[r] += __shfl_xor(rs[r], off, 64);
        if (lm == 0) {
#pragma unroll
            for (int r = 0; r < 4; r++) a_out[r0 + mt * 16 + qq * 4 + r] = rs[r];
        }
    }
}

// ---------------- k3: softmax over batch dim (in-place a -> alpha) ----------------
__global__ __launch_bounds__(256) void k3_softmax(float* __restrict__ a,
                                                  const int* __restrict__ idx) {
    int n = blockIdx.x;
    int tid = threadIdx.x;
    constexpr int PER = BB / 256;  // 16
    float vals[PER];
    float m = -1e30f;
#pragma unroll
    for (int i = 0; i < PER; i++) {
        int b = i * 256 + tid;
        vals[i] = a[b * NN + n];
        m = fmaxf(m, vals[i]);
    }
    __shared__ float red[8];
#pragma unroll
    for (int off = 32; off >= 1; off >>= 1) m = fmaxf(m, __shfl_xor(m, off, 64));
    int wave = tid >> 6;
    if ((tid & 63) == 0) red[wave] = m;
    __syncthreads();
    m = fmaxf(fmaxf(red[0], red[1]), fmaxf(red[2], red[3]));

    float s = 0.f;
#pragma unroll
    for (int i = 0; i < PER; i++) {
        vals[i] = expf(vals[i] - m);
        s += vals[i];
    }
#pragma unroll
    for (int off = 32; off >= 1; off >>= 1) s += __shfl_xor(s, off, 64);
    if ((tid & 63) == 0) red[4 + wave] = s;
    __syncthreads();
    s = red[4] + red[5] + red[6] + red[7];
    float inv = 1.f / s;
#pragma unroll
    for (int i = 0; i < PER; i++) {
        int b = i * 256 + tid;
        float msk = (idx[b * NN + n] != 0) ? 1.f : 0.f;
        a[b * NN + n] = vals[i] * inv * msk;
    }
}

// ---------------- k4: weighted pooling, vectorized ----------------
__global__ __launch_bounds__(128) void k4_pool(
    const float* __restrict__ alpha, const unsigned short* __restrict__ C,
    float* __restrict__ out)
{
    int b = blockIdx.x;
    int tid = threadIdx.x;
    __shared__ float al[NN];
    if (tid < NN) al[tid] = alpha[b * NN + tid];
    __syncthreads();
    if (tid < 100) {
        int f = tid * 4;
        float s0 = 0.f, s1 = 0.f, s2 = 0.f, s3 = 0.f;
        const unsigned short* Cb = C + (size_t)b * (NN * FILT) + f;
#pragma unroll
        for (int n = 0; n < NN; n++) {
            u16x4 c = *(const u16x4*)(Cb + (size_t)n * FILT);
            float a = al[n];
            s0 = fmaf(a, bf2f(c[0]), s0);
            s1 = fmaf(a, bf2f(c[1]), s1);
            s2 = fmaf(a, bf2f(c[2]), s2);
            s3 = fmaf(a, bf2f(c[3]), s3);
        }
        float4 o; o.x = s0; o.y = s1; o.z = s2; o.w = s3;
        *(float4*)(out + (size_t)b * FILT + f) = o;
    }
}

extern "C" void kernel_launch(void* const* d_in, const int* in_sizes, int n_in,
                              void* d_out, int out_size, void* d_ws, size_t ws_size,
                              hipStream_t stream) {
    const int*   idx    = (const int*)d_in[0];
    const float* emb    = (const float*)d_in[1];
    const float* conv_w = (const float*)d_in[2];
    const float* conv_b = (const float*)d_in[3];
    const float* v      = (const float*)d_in[4];
    const float* vb     = (const float*)d_in[5];
    const float* q      = (const float*)d_in[6];
    float* out = (float*)d_out;

    // workspace (total 99,247,104 B <= 99,287,040 proven floor):
    //   Bv2 | vbp | qp | Bc2 (aliased by a_buf after k1) | Cws (+39.9 KB slack for k2 row overrun)
    char* ws = (char*)d_ws;
    size_t o = 0;
    unsigned short* Bv2 = (unsigned short*)(ws + o); o += (size_t)169 * 512 * 2;      // 173,056
    float* vbp = (float*)(ws + o);                   o += 1024;
    float* qp  = (float*)(ws + o);                   o += 1024;                        // 175,104
    unsigned short* Bc2 = (unsigned short*)(ws + o);
    float* a_buf = (float*)(ws + o);                 // alias of Bc2 (491,520 <= 768,000)
    o += (size_t)750 * 512 * 2;                      // -> 943,104
    unsigned short* Cws = (unsigned short*)(ws + o);

    const int NP = 750 * 512 + 169 * 512;            // 470,528
    kP<<<(NP + 255) / 256, 256, 0, stream>>>(conv_w, v, vb, q, Bc2, Bv2, vbp, qp);
    k1_conv<<<BB / 2, 320, 0, stream>>>(idx, emb, Bc2, conv_b, Cws);
    k2_att<<<(BB * NN) / 128, 256, 0, stream>>>(Cws, Bv2, vbp, qp, a_buf);
    k3_softmax<<<NN, 256, 0, stream>>>(a_buf, idx);
    k4_pool<<<BB, 128, 0, stream>>>(a_buf, Cws, out);
}

// Round 6
// 411.239 us; speedup vs baseline: 6.8966x; 1.1015x over previous
//
#include <hip/hip_runtime.h>
#include <hip/hip_bf16.h>

#define VOCAB 50000
#define EMB   300
#define FILT  400
#define ATT   200
#define BB    4096
#define NN    30

#define ATTP  208        // att padded to 13 n-tiles
#define KC    416        // padded K for attention GEMM (13 K-steps of 32)
#define AST   168        // LDS A-stage row stride (ushorts) per K-half (160 data + 8 pad)

typedef short bf16x8 __attribute__((ext_vector_type(8)));
typedef float f32x4  __attribute__((ext_vector_type(4)));
typedef unsigned short u16x4 __attribute__((ext_vector_type(4)));

static __device__ __forceinline__ unsigned short f2bf(float f) {
    __hip_bfloat16 h = __float2bfloat16(f);
    union { __hip_bfloat16 h; unsigned short u; } c; c.h = h; return c.u;
}
static __device__ __forceinline__ float bf2f(unsigned short u) {
    union { unsigned int u; float f; } c; c.u = ((unsigned int)u) << 16; return c.f;
}
// numerics validated (R3 first-pass absmax 3.8e-6)
static __device__ __forceinline__ float fast_tanh(float x) {
    float e = __expf(2.f * x);
    return 1.f - 2.f * __builtin_amdgcn_rcpf(e + 1.f);
}

// ---------------- prep: fragment-major Bc2 [750 tiles][512], Bv2 [169 tiles][512], vbp/qp ----------------
// Bc2 tile t=(k*10+es)*25+ft holds B[f=ft*16+lm][e=es*32+qq*8+j] at offset lm*32+qq*8+j.
// Bv2 tile t=ks*13+at holds v[f=ks*32+qq*8+j][att=at*16+lm] at same offset.
__global__ __launch_bounds__(256) void kP(const float* __restrict__ conv_w,
                                          const float* __restrict__ v,
                                          const float* __restrict__ vb,
                                          const float* __restrict__ q,
                                          unsigned short* __restrict__ Bc2,
                                          unsigned short* __restrict__ Bv2,
                                          float* __restrict__ vbp,
                                          float* __restrict__ qp) {
    int t = blockIdx.x * 256 + threadIdx.x;
    const int NBC = 750 * 512;               // 384,000
    if (t < NBC) {
        int tau = t >> 9, off = t & 511;
        int lm = off >> 5, qq = (off >> 3) & 3, j = off & 7;
        int ft = tau % 25, es = (tau / 25) % 10, k = tau / 250;
        int f = ft * 16 + lm;
        int e = es * 32 + qq * 8 + j;
        float val = (e < EMB) ? conv_w[((size_t)f * EMB + e) * 3 + k] : 0.f;
        Bc2[t] = f2bf(val);
    } else {
        int t2 = t - NBC;
        if (t2 < 169 * 512) {                // 86,528
            int tau = t2 >> 9, off = t2 & 511;
            int lm = off >> 5, qq = (off >> 3) & 3, j = off & 7;
            int ks = tau / 13, at = tau % 13;
            int att = at * 16 + lm;
            int fcol = ks * 32 + qq * 8 + j;
            float val = (att < ATT && fcol < FILT) ? v[(size_t)fcol * ATT + att] : 0.f;
            Bv2[t2] = f2bf(val);
        }
    }
    if (t < ATTP) {
        vbp[t] = (t < ATT) ? vb[t] : 0.f;
        qp[t]  = (t < ATT) ? q[t] : 0.f;
    }
}

// ---------------- k1: conv GEMM, M=128/block, K-halved LDS A-stage, bF prefetch ----------------
// block = 640 thr (10 waves) = 2 row-groups (64 rows) x 5 f-waves (80 f).
// LDS row j (0..127): batch j>>5, padded pos j&31 (0=left pad, 1..30=tokens, 31=right pad).
// Rows 128..130 zero (read only by discarded GEMM rows 126/127 k-shifts).
// Each half stages e in [half*160, half*160+160); B tiles zero for e>=300 kill tail garbage.
__global__ __launch_bounds__(640, 2) void k1_conv(
    const int* __restrict__ idx,
    const float* __restrict__ emb,
    const unsigned short* __restrict__ Bc2,
    const float* __restrict__ conv_b,
    unsigned short* __restrict__ Cws)
{
    __shared__ unsigned short As[131 * AST];   // 44,016 B
    const int bid = blockIdx.x;
    const int t = threadIdx.x;
    const int lane = t & 63;
    const int wave = t >> 6;          // 0..9
    const int lm = lane & 15;
    const int qq = lane >> 4;
    const int laneoff = lm * 32 + qq * 8;
    const int fwave = wave % 5;
    const int wg = wave / 5;
    const int wave5 = fwave * 5;
    const int rbase = wg * 64;

    f32x4 acc[4][5];
#pragma unroll
    for (int mt = 0; mt < 4; mt++)
#pragma unroll
        for (int nt = 0; nt < 5; nt++)
            acc[mt][nt] = (f32x4){0.f, 0.f, 0.f, 0.f};

    for (int half = 0; half < 2; ++half) {
        if (half) __syncthreads();           // all reads of previous half done

        // ---- stage A half: 131 rows x 20 chunks of 8 elems ----
        for (int u = t; u < 131 * 20; u += 640) {
            int j = u / 20, ch = u - (u / 20) * 20;
            int e = half * 160 + ch * 8;
            bf16x8 val = (bf16x8){0, 0, 0, 0, 0, 0, 0, 0};
            if (j < 128) {
                int bloc = j >> 5, j2 = j & 31;
                if (j2 >= 1 && j2 <= 30 && e < 300) {
                    int tok = idx[(bid * 4 + bloc) * NN + (j2 - 1)];
                    float f[8];
                    if (e <= 292) {
                        float4 x = *(const float4*)(emb + (size_t)tok * EMB + e);
                        float4 y = *(const float4*)(emb + (size_t)tok * EMB + e + 4);
                        f[0] = x.x; f[1] = x.y; f[2] = x.z; f[3] = x.w;
                        f[4] = y.x; f[5] = y.y; f[6] = y.z; f[7] = y.w;
                    } else {
#pragma unroll
                        for (int jj = 0; jj < 8; jj++) {
                            int ee = e + jj;
                            f[jj] = (ee < EMB) ? emb[(size_t)tok * EMB + ee] : 0.f;
                        }
                    }
#pragma unroll
                    for (int jj = 0; jj < 8; jj++) val[jj] = (short)f2bf(f[jj]);
                }
            }
            *(bf16x8*)(As + j * AST + ch * 8) = val;
        }
        __syncthreads();

        // ---- K-loop over this half: 5 e-groups x 3 k, depth-1 bF prefetch ----
        const int es0 = half * 5;
        bf16x8 bF[5];
#pragma unroll
        for (int nt = 0; nt < 5; nt++)
            bF[nt] = *(const bf16x8*)(Bc2 + ((size_t)((0 * 10 + es0) * 25 + wave5 + nt)) * 512 + laneoff);

#pragma unroll
        for (int eg = 0; eg < 5; ++eg) {
#pragma unroll
            for (int k = 0; k < 3; ++k) {
                // prefetch next group's B (clamped at the very last group)
                int kn = k + 1, egn = eg;
                if (kn == 3) { kn = 0; egn = eg + 1; }
                if (egn == 5) { egn = 4; kn = 2; }
                bf16x8 bFn[5];
#pragma unroll
                for (int nt = 0; nt < 5; nt++)
                    bFn[nt] = *(const bf16x8*)(Bc2 + ((size_t)((kn * 10 + es0 + egn) * 25 + wave5 + nt)) * 512 + laneoff);

                bf16x8 aF[4];
#pragma unroll
                for (int mt = 0; mt < 4; mt++)
                    aF[mt] = *(const bf16x8*)(As + (rbase + mt * 16 + lm + k) * AST + eg * 32 + 8 * qq);

#pragma unroll
                for (int nt = 0; nt < 5; nt++)
#pragma unroll
                    for (int mt = 0; mt < 4; mt++)
                        acc[mt][nt] = __builtin_amdgcn_mfma_f32_16x16x32_bf16(aF[mt], bF[nt], acc[mt][nt], 0, 0, 0);

#pragma unroll
                for (int nt = 0; nt < 5; nt++) bF[nt] = bFn[nt];
            }
        }
    }

    // ---- epilogue: bias + relu -> global Cws (bf16) ----
    const int f0 = fwave * 80;
    float cb[5];
#pragma unroll
    for (int nt = 0; nt < 5; nt++) cb[nt] = conv_b[f0 + nt * 16 + lm];
#pragma unroll
    for (int mt = 0; mt < 4; mt++) {
#pragma unroll
        for (int r = 0; r < 4; r++) {
            int lrow = rbase + mt * 16 + qq * 4 + r;
            int n = lrow & 31;
            int bglob = bid * 4 + (lrow >> 5);
            if (n < NN) {
#pragma unroll
                for (int nt = 0; nt < 5; nt++) {
                    float vv = fmaxf(acc[mt][nt][r] + cb[nt], 0.f);
                    Cws[((size_t)bglob * NN + n) * FILT + f0 + nt * 16 + lm] = f2bf(vv);
                }
            }
        }
    }
}

// ---------------- k2: attention logits GEMM (R5-verbatim, proven) ----------------
__global__ __launch_bounds__(256, 2) void k2_att(
    const unsigned short* __restrict__ Cws,
    const unsigned short* __restrict__ Bv2,
    const float* __restrict__ vbp, const float* __restrict__ qp,
    float* __restrict__ a_out)
{
    const int lane = threadIdx.x & 63;
    const int wave = threadIdx.x >> 6;
    const int lm = lane & 15, qq = lane >> 4;
    const int laneoff = lm * 32 + qq * 8;
    const int r0 = blockIdx.x * 128 + wave * 32;

    f32x4 acc[2][13];
#pragma unroll
    for (int mt = 0; mt < 2; mt++)
#pragma unroll
        for (int nt = 0; nt < 13; nt++) acc[mt][nt] = (f32x4){0.f, 0.f, 0.f, 0.f};

#pragma unroll 1
    for (int ks = 0; ks < 13; ks++) {
        bf16x8 bF[13];
#pragma unroll
        for (int nt = 0; nt < 13; nt++)
            bF[nt] = *(const bf16x8*)(Bv2 + ((size_t)(ks * 13 + nt)) * 512 + laneoff);
        bf16x8 aF[2];
#pragma unroll
        for (int mt = 0; mt < 2; mt++)   // cols >=400 overrun into next row; Bv2 rows there are 0
            aF[mt] = *(const bf16x8*)(Cws + (size_t)(r0 + mt * 16 + lm) * FILT + ks * 32 + 8 * qq);
#pragma unroll
        for (int nt = 0; nt < 13; nt++)
#pragma unroll
            for (int mt = 0; mt < 2; mt++)
                acc[mt][nt] = __builtin_amdgcn_mfma_f32_16x16x32_bf16(aF[mt], bF[nt], acc[mt][nt], 0, 0, 0);
    }

#pragma unroll
    for (int mt = 0; mt < 2; mt++) {
        float rs[4] = {0.f, 0.f, 0.f, 0.f};
#pragma unroll
        for (int nt = 0; nt < 13; nt++) {
            int att = nt * 16 + lm;
            float vbv = vbp[att], qv = qp[att];
#pragma unroll
            for (int r = 0; r < 4; r++)
                rs[r] += fast_tanh(acc[mt][nt][r] + vbv) * qv;   // padded att: acc=0,q=0 -> 0
        }
#pragma unroll
        for (int off = 1; off < 16; off <<= 1)
#pragma unroll
            for (int r = 0; r < 4; r++) rs[r] += __shfl_xor(rs[r], off, 64);
        if (lm == 0) {
#pragma unroll
            for (int r = 0; r < 4; r++) a_out[r0 + mt * 16 + qq * 4 + r] = rs[r];
        }
    }
}

// ---------------- k3: softmax over batch dim (in-place a -> alpha) ----------------
__global__ __launch_bounds__(256) void k3_softmax(float* __restrict__ a,
                                                  const int* __restrict__ idx) {
    int n = blockIdx.x;
    int tid = threadIdx.x;
    constexpr int PER = BB / 256;  // 16
    float vals[PER];
    float m = -1e30f;
#pragma unroll
    for (int i = 0; i < PER; i++) {
        int b = i * 256 + tid;
        vals[i] = a[b * NN + n];
        m = fmaxf(m, vals[i]);
    }
    __shared__ float red[8];
#pragma unroll
    for (int off = 32; off >= 1; off >>= 1) m = fmaxf(m, __shfl_xor(m, off, 64));
    int wave = tid >> 6;
    if ((tid & 63) == 0) red[wave] = m;
    __syncthreads();
    m = fmaxf(fmaxf(red[0], red[1]), fmaxf(red[2], red[3]));

    float s = 0.f;
#pragma unroll
    for (int i = 0; i < PER; i++) {
        vals[i] = expf(vals[i] - m);
        s += vals[i];
    }
#pragma unroll
    for (int off = 32; off >= 1; off >>= 1) s += __shfl_xor(s, off, 64);
    if ((tid & 63) == 0) red[4 + wave] = s;
    __syncthreads();
    s = red[4] + red[5] + red[6] + red[7];
    float inv = 1.f / s;
#pragma unroll
    for (int i = 0; i < PER; i++) {
        int b = i * 256 + tid;
        float msk = (idx[b * NN + n] != 0) ? 1.f : 0.f;
        a[b * NN + n] = vals[i] * inv * msk;
    }
}

// ---------------- k4: weighted pooling, vectorized ----------------
__global__ __launch_bounds__(128) void k4_pool(
    const float* __restrict__ alpha, const unsigned short* __restrict__ C,
    float* __restrict__ out)
{
    int b = blockIdx.x;
    int tid = threadIdx.x;
    __shared__ float al[NN];
    if (tid < NN) al[tid] = alpha[b * NN + tid];
    __syncthreads();
    if (tid < 100) {
        int f = tid * 4;
        float s0 = 0.f, s1 = 0.f, s2 = 0.f, s3 = 0.f;
        const unsigned short* Cb = C + (size_t)b * (NN * FILT) + f;
#pragma unroll
        for (int n = 0; n < NN; n++) {
            u16x4 c = *(const u16x4*)(Cb + (size_t)n * FILT);
            float a = al[n];
            s0 = fmaf(a, bf2f(c[0]), s0);
            s1 = fmaf(a, bf2f(c[1]), s1);
            s2 = fmaf(a, bf2f(c[2]), s2);
            s3 = fmaf(a, bf2f(c[3]), s3);
        }
        float4 o; o.x = s0; o.y = s1; o.z = s2; o.w = s3;
        *(float4*)(out + (size_t)b * FILT + f) = o;
    }
}

extern "C" void kernel_launch(void* const* d_in, const int* in_sizes, int n_in,
                              void* d_out, int out_size, void* d_ws, size_t ws_size,
                              hipStream_t stream) {
    const int*   idx    = (const int*)d_in[0];
    const float* emb    = (const float*)d_in[1];
    const float* conv_w = (const float*)d_in[2];
    const float* conv_b = (const float*)d_in[3];
    const float* v      = (const float*)d_in[4];
    const float* vb     = (const float*)d_in[5];
    const float* q      = (const float*)d_in[6];
    float* out = (float*)d_out;

    // workspace (total 99,247,104 B <= 99,287,040 proven floor):
    //   Bv2 | vbp | qp | Bc2 (aliased by a_buf after k1) | Cws (+ slack for k2 row overrun)
    char* ws = (char*)d_ws;
    size_t o = 0;
    unsigned short* Bv2 = (unsigned short*)(ws + o); o += (size_t)169 * 512 * 2;      // 173,056
    float* vbp = (float*)(ws + o);                   o += 1024;
    float* qp  = (float*)(ws + o);                   o += 1024;                        // 175,104
    unsigned short* Bc2 = (unsigned short*)(ws + o);
    float* a_buf = (float*)(ws + o);                 // alias of Bc2 (491,520 <= 768,000)
    o += (size_t)750 * 512 * 2;                      // -> 943,104
    unsigned short* Cws = (unsigned short*)(ws + o);

    const int NP = 750 * 512 + 169 * 512;            // 470,528
    kP<<<(NP + 255) / 256, 256, 0, stream>>>(conv_w, v, vb, q, Bc2, Bv2, vbp, qp);
    k1_conv<<<BB / 4, 640, 0, stream>>>(idx, emb, Bc2, conv_b, Cws);
    k2_att<<<(BB * NN) / 128, 256, 0, stream>>>(Cws, Bv2, vbp, qp, a_buf);
    k3_softmax<<<NN, 256, 0, stream>>>(a_buf, idx);
    k4_pool<<<BB, 128, 0, stream>>>(a_buf, Cws, out);
}

// Round 7
// 278.947 us; speedup vs baseline: 10.1673x; 1.4743x over previous
//
#include <hip/hip_runtime.h>
#include <hip/hip_bf16.h>

#define VOCAB 50000
#define EMB   300
#define FILT  400
#define ATT   200
#define BB    4096
#define NN    30

#define ATTP  208        // att padded to 13 n-tiles
#define KC    416        // padded K for attention GEMM (13 K-steps of 32)

typedef short bf16x8 __attribute__((ext_vector_type(8)));
typedef float f32x4  __attribute__((ext_vector_type(4)));
typedef unsigned short u16x4 __attribute__((ext_vector_type(4)));

static __device__ __forceinline__ unsigned short f2bf(float f) {
    __hip_bfloat16 h = __float2bfloat16(f);
    union { __hip_bfloat16 h; unsigned short u; } c; c.h = h; return c.u;
}
static __device__ __forceinline__ float bf2f(unsigned short u) {
    union { unsigned int u; float f; } c; c.u = ((unsigned int)u) << 16; return c.f;
}
// numerics validated (R3 first-pass absmax 3.8e-6)
static __device__ __forceinline__ float fast_tanh(float x) {
    float e = __expf(2.f * x);
    return 1.f - 2.f * __builtin_amdgcn_rcpf(e + 1.f);
}

// async global->LDS DMA, 16 B per lane; lds dest = wave-uniform base + lane*16
static __device__ __forceinline__ void dma16(const unsigned short* g, unsigned short* l) {
    __builtin_amdgcn_global_load_lds(
        (const __attribute__((address_space(1))) unsigned int*)(const void*)g,
        (__attribute__((address_space(3))) unsigned int*)(void*)l,
        16, 0, 0);
}

// ---------------- prep: lane-major fragment tiles ----------------
// Bc2 tile tau=(k*10+es)*25+ft, 512 ushorts; pos = lane*8+j holds
//   B[f=ft*16+(lane&15)][e=es*32+(lane>>4)*8+j]  (zero for e>=300)
// Bv2 tile tau=ks*13+at; pos = lane*8+j holds
//   v[fcol=ks*32+(lane>>4)*8+j][att=at*16+(lane&15)]  (zero-padded)
// -> a wave DMA/ds_read of one tile is a verbatim contiguous 1 KB.
__global__ __launch_bounds__(256) void kP(const float* __restrict__ conv_w,
                                          const float* __restrict__ v,
                                          const float* __restrict__ vb,
                                          const float* __restrict__ q,
                                          unsigned short* __restrict__ Bc2,
                                          unsigned short* __restrict__ Bv2,
                                          float* __restrict__ vbp,
                                          float* __restrict__ qp) {
    int t = blockIdx.x * 256 + threadIdx.x;
    const int NBC = 750 * 512;               // 384,000
    if (t < NBC) {
        int tau = t >> 9, off = t & 511;
        int l = off >> 3, j = off & 7;
        int lm = l & 15, qq = l >> 4;
        int ft = tau % 25, es = (tau / 25) % 10, k = tau / 250;
        int f = ft * 16 + lm;
        int e = es * 32 + qq * 8 + j;
        float val = (e < EMB) ? conv_w[((size_t)f * EMB + e) * 3 + k] : 0.f;
        Bc2[t] = f2bf(val);
    } else {
        int t2 = t - NBC;
        if (t2 < 169 * 512) {                // 86,528
            int tau = t2 >> 9, off = t2 & 511;
            int l = off >> 3, j = off & 7;
            int lm = l & 15, qq = l >> 4;
            int ks = tau / 13, at = tau % 13;
            int att = at * 16 + lm;
            int fcol = ks * 32 + qq * 8 + j;
            float val = (att < ATT && fcol < FILT) ? v[(size_t)fcol * ATT + att] : 0.f;
            Bv2[t2] = f2bf(val);
        }
    }
    if (t < ATTP) {
        vbp[t] = (t < ATT) ? vb[t] : 0.f;
        qp[t]  = (t < ATT) ? q[t] : 0.f;
    }
}

// gather 8 consecutive emb cols (fp32) for one token into aR; zeros when invalid
static __device__ __forceinline__ void gatherA(const float* __restrict__ emb,
                                               int tok, int e, float* aR) {
#pragma unroll
    for (int jj = 0; jj < 8; jj++) aR[jj] = 0.f;
    if (tok >= 0 && e < EMB) {
        if (e <= 292) {
            float4 x = *(const float4*)(emb + (size_t)tok * EMB + e);
            float4 y = *(const float4*)(emb + (size_t)tok * EMB + e + 4);
            aR[0] = x.x; aR[1] = x.y; aR[2] = x.z; aR[3] = x.w;
            aR[4] = y.x; aR[5] = y.y; aR[6] = y.z; aR[7] = y.w;
        } else {
#pragma unroll
            for (int jj = 0; jj < 8; jj++) {
                int ee = e + jj;
                if (ee < EMB) aR[jj] = emb[(size_t)tok * EMB + ee];
            }
        }
    }
}

// ---------------- k1: m97-style pipelined conv GEMM ----------------
// 1024 blocks x 640 thr (10 waves = 2 row-groups x 5 f-waves), M=128 (4 batches).
// 30 K-steps of 32 (10 e-chunks x 3 taps). B: DMA double-buffer, one barrier/step,
// DMA for step s+2 issued after barrier s (drained one full step later).
// A: 32e chunk in LDS (rows 0..130; row j = batch j>>5, padded pos j&31),
// register-prefetched one chunk ahead.
__global__ __launch_bounds__(640, 2) void k1_conv(
    const int* __restrict__ idx,
    const float* __restrict__ emb,
    const unsigned short* __restrict__ Bc2,
    const float* __restrict__ conv_b,
    unsigned short* __restrict__ Cws)
{
    __shared__ unsigned short As[131 * 40];       // 10,480 B (stride 40 ush = 20 dw, 2-way-free)
    __shared__ unsigned short Bs[2 * 25 * 512];   // 51,200 B
    const int bid = blockIdx.x;
    const int t = threadIdx.x;
    const int lane = t & 63, wave = t >> 6;
    const int lm = lane & 15, qq = lane >> 4;
    const int wg = wave / 5, fw = wave % 5;
    const int rbase = wg * 64;

    // A-gather unit: thread t -> row uj, 8-col segment useg
    const int uj = t >> 2, useg = t & 3;
    const bool uact = (t < 524);                  // 131 rows x 4 segs
    int utok = -1;
    if (uact && uj < 128) {
        int ub = uj >> 5, uj2 = uj & 31;
        if (uj2 >= 1 && uj2 <= 30) utok = idx[(bid * 4 + ub) * NN + (uj2 - 1)];
    }

    // prologue: DMA K-steps 0,1 (wg0 waves stage their own 5 f-tiles)
    if (wg == 0) {
#pragma unroll
        for (int s = 0; s < 2; s++) {
#pragma unroll
            for (int nt = 0; nt < 5; nt++) {
                int gt = (s % 3) * 250 + (s / 3) * 25 + fw * 5 + nt;   // (k*10+es)*25+ft
                dma16(Bc2 + (size_t)gt * 512 + lane * 8,
                      Bs + s * 12800 + (fw * 5 + nt) * 512);
            }
        }
    }
    float aR[8];
    gatherA(emb, utok, useg * 8, aR);             // chunk 0

    f32x4 acc[4][5];
#pragma unroll
    for (int mt = 0; mt < 4; mt++)
#pragma unroll
        for (int nt = 0; nt < 5; nt++)
            acc[mt][nt] = (f32x4){0.f, 0.f, 0.f, 0.f};

    for (int es = 0; es < 10; ++es) {
        // publish A chunk es (aR loaded >= 1 full chunk ago)
        if (uact) {
            union { bf16x8 v; unsigned short u[8]; } cv;
#pragma unroll
            for (int jj = 0; jj < 8; jj++) cv.u[jj] = f2bf(aR[jj]);
            *(bf16x8*)(As + uj * 40 + useg * 8) = cv.v;
        }
        __syncthreads();                           // As visible; also drains pending DMA
        if (es < 9) gatherA(emb, utok, (es + 1) * 32 + useg * 8, aR);

#pragma unroll
        for (int k = 0; k < 3; ++k) {
            const int s = es * 3 + k;
            const unsigned short* bb = Bs + (s & 1) * 12800;
            bf16x8 aF[4];
#pragma unroll
            for (int mt = 0; mt < 4; mt++)
                aF[mt] = *(const bf16x8*)(As + (rbase + mt * 16 + lm + k) * 40 + qq * 8);
#pragma unroll
            for (int nt = 0; nt < 5; nt++) {
                bf16x8 bF = *(const bf16x8*)(bb + (fw * 5 + nt) * 512 + lane * 8);
#pragma unroll
                for (int mt = 0; mt < 4; mt++)
                    acc[mt][nt] = __builtin_amdgcn_mfma_f32_16x16x32_bf16(aF[mt], bF, acc[mt][nt], 0, 0, 0);
            }
            __syncthreads();                       // buf[s&1] free; DMA(s+1) already drained
            if (s + 2 < 30 && wg == 0) {
                const int s2 = s + 2, es2 = s2 / 3, k2 = s2 - es2 * 3;
#pragma unroll
                for (int nt = 0; nt < 5; nt++) {
                    int gt = (k2 * 10 + es2) * 25 + fw * 5 + nt;
                    dma16(Bc2 + (size_t)gt * 512 + lane * 8,
                          Bs + (s & 1) * 12800 + (fw * 5 + nt) * 512);
                }
            }
        }
    }

    // epilogue: bias + relu -> Cws (bf16)
    const int f0 = fw * 80;
    float cb[5];
#pragma unroll
    for (int nt = 0; nt < 5; nt++) cb[nt] = conv_b[f0 + nt * 16 + lm];
#pragma unroll
    for (int mt = 0; mt < 4; mt++) {
#pragma unroll
        for (int r = 0; r < 4; r++) {
            int lrow = rbase + mt * 16 + qq * 4 + r;
            int n = lrow & 31;
            int bglob = bid * 4 + (lrow >> 5);
            if (n < NN) {
#pragma unroll
                for (int nt = 0; nt < 5; nt++) {
                    float vv = fmaxf(acc[mt][nt][r] + cb[nt], 0.f);
                    Cws[((size_t)bglob * NN + n) * FILT + f0 + nt * 16 + lm] = f2bf(vv);
                }
            }
        }
    }
}

// ---------------- k2: pipelined attention-logit GEMM ----------------
// 960 blocks x 256 thr (4 waves x 32 rows), N=208, 13 K-steps of 32.
// B: DMA double-buffer (tiles split round-robin over waves); aF: depth-1 reg prefetch.
__global__ __launch_bounds__(256, 2) void k2_att(
    const unsigned short* __restrict__ Cws,
    const unsigned short* __restrict__ Bv2,
    const float* __restrict__ vbp, const float* __restrict__ qp,
    float* __restrict__ a_out)
{
    __shared__ unsigned short Bs[2 * 13 * 512];   // 26,624 B
    const int lane = threadIdx.x & 63;
    const int wave = threadIdx.x >> 6;
    const int lm = lane & 15, qq = lane >> 4;
    const int r0 = blockIdx.x * 128 + wave * 32;

#pragma unroll
    for (int s = 0; s < 2; s++)
#pragma unroll
        for (int nt = 0; nt < 13; nt++)
            if ((nt & 3) == wave)
                dma16(Bv2 + (size_t)(s * 13 + nt) * 512 + lane * 8,
                      Bs + s * 6656 + nt * 512);

    bf16x8 aFc[2], aFn[2];
#pragma unroll
    for (int mt = 0; mt < 2; mt++)    // col overrun >=400 reads next row; B rows there are zero
        aFc[mt] = *(const bf16x8*)(Cws + (size_t)(r0 + mt * 16 + lm) * FILT + 8 * qq);

    f32x4 acc[2][13];
#pragma unroll
    for (int mt = 0; mt < 2; mt++)
#pragma unroll
        for (int nt = 0; nt < 13; nt++) acc[mt][nt] = (f32x4){0.f, 0.f, 0.f, 0.f};

    __syncthreads();                               // drains DMA 0,1

    for (int ks = 0; ks < 13; ++ks) {
        if (ks < 12)
#pragma unroll
            for (int mt = 0; mt < 2; mt++)
                aFn[mt] = *(const bf16x8*)(Cws + (size_t)(r0 + mt * 16 + lm) * FILT + (ks + 1) * 32 + 8 * qq);
        const unsigned short* bb = Bs + (ks & 1) * 6656;
#pragma unroll
        for (int nt = 0; nt < 13; nt++) {
            bf16x8 bF = *(const bf16x8*)(bb + nt * 512 + lane * 8);
#pragma unroll
            for (int mt = 0; mt < 2; mt++)
                acc[mt][nt] = __builtin_amdgcn_mfma_f32_16x16x32_bf16(aFc[mt], bF, acc[mt][nt], 0, 0, 0);
        }
        __syncthreads();
        if (ks + 2 < 13)
#pragma unroll
            for (int nt = 0; nt < 13; nt++)
                if ((nt & 3) == wave)
                    dma16(Bv2 + (size_t)((ks + 2) * 13 + nt) * 512 + lane * 8,
                          Bs + (ks & 1) * 6656 + nt * 512);
#pragma unroll
        for (int mt = 0; mt < 2; mt++) aFc[mt] = aFn[mt];
    }

#pragma unroll
    for (int mt = 0; mt < 2; mt++) {
        float rs[4] = {0.f, 0.f, 0.f, 0.f};
#pragma unroll
        for (int nt = 0; nt < 13; nt++) {
            int att = nt * 16 + lm;
            float vbv = vbp[att], qv = qp[att];
#pragma unroll
            for (int r = 0; r < 4; r++)
                rs[r] += fast_tanh(acc[mt][nt][r] + vbv) * qv;   // padded att: acc=0,q=0 -> 0
        }
#pragma unroll
        for (int off = 1; off < 16; off <<= 1)
#pragma unroll
            for (int r = 0; r < 4; r++) rs[r] += __shfl_xor(rs[r], off, 64);
        if (lm == 0) {
#pragma unroll
            for (int r = 0; r < 4; r++) a_out[r0 + mt * 16 + qq * 4 + r] = rs[r];
        }
    }
}

// ---------------- k3: softmax over batch dim (in-place a -> alpha) ----------------
__global__ __launch_bounds__(256) void k3_softmax(float* __restrict__ a,
                                                  const int* __restrict__ idx) {
    int n = blockIdx.x;
    int tid = threadIdx.x;
    constexpr int PER = BB / 256;  // 16
    float vals[PER];
    float m = -1e30f;
#pragma unroll
    for (int i = 0; i < PER; i++) {
        int b = i * 256 + tid;
        vals[i] = a[b * NN + n];
        m = fmaxf(m, vals[i]);
    }
    __shared__ float red[8];
#pragma unroll
    for (int off = 32; off >= 1; off >>= 1) m = fmaxf(m, __shfl_xor(m, off, 64));
    int wave = tid >> 6;
    if ((tid & 63) == 0) red[wave] = m;
    __syncthreads();
    m = fmaxf(fmaxf(red[0], red[1]), fmaxf(red[2], red[3]));

    float s = 0.f;
#pragma unroll
    for (int i = 0; i < PER; i++) {
        vals[i] = expf(vals[i] - m);
        s += vals[i];
    }
#pragma unroll
    for (int off = 32; off >= 1; off >>= 1) s += __shfl_xor(s, off, 64);
    if ((tid & 63) == 0) red[4 + wave] = s;
    __syncthreads();
    s = red[4] + red[5] + red[6] + red[7];
    float inv = 1.f / s;
#pragma unroll
    for (int i = 0; i < PER; i++) {
        int b = i * 256 + tid;
        float msk = (idx[b * NN + n] != 0) ? 1.f : 0.f;
        a[b * NN + n] = vals[i] * inv * msk;
    }
}

// ---------------- k4: weighted pooling, vectorized ----------------
__global__ __launch_bounds__(128) void k4_pool(
    const float* __restrict__ alpha, const unsigned short* __restrict__ C,
    float* __restrict__ out)
{
    int b = blockIdx.x;
    int tid = threadIdx.x;
    __shared__ float al[NN];
    if (tid < NN) al[tid] = alpha[b * NN + tid];
    __syncthreads();
    if (tid < 100) {
        int f = tid * 4;
        float s0 = 0.f, s1 = 0.f, s2 = 0.f, s3 = 0.f;
        const unsigned short* Cb = C + (size_t)b * (NN * FILT) + f;
#pragma unroll
        for (int n = 0; n < NN; n++) {
            u16x4 c = *(const u16x4*)(Cb + (size_t)n * FILT);
            float a = al[n];
            s0 = fmaf(a, bf2f(c[0]), s0);
            s1 = fmaf(a, bf2f(c[1]), s1);
            s2 = fmaf(a, bf2f(c[2]), s2);
            s3 = fmaf(a, bf2f(c[3]), s3);
        }
        float4 o; o.x = s0; o.y = s1; o.z = s2; o.w = s3;
        *(float4*)(out + (size_t)b * FILT + f) = o;
    }
}

extern "C" void kernel_launch(void* const* d_in, const int* in_sizes, int n_in,
                              void* d_out, int out_size, void* d_ws, size_t ws_size,
                              hipStream_t stream) {
    const int*   idx    = (const int*)d_in[0];
    const float* emb    = (const float*)d_in[1];
    const float* conv_w = (const float*)d_in[2];
    const float* conv_b = (const float*)d_in[3];
    const float* v      = (const float*)d_in[4];
    const float* vb     = (const float*)d_in[5];
    const float* q      = (const float*)d_in[6];
    float* out = (float*)d_out;

    // workspace (total 99,247,104 B <= 99,287,040 proven floor):
    //   Bv2 | vbp | qp | Bc2 (aliased by a_buf after k1) | Cws (+ slack for k2 row overrun)
    char* ws = (char*)d_ws;
    size_t o = 0;
    unsigned short* Bv2 = (unsigned short*)(ws + o); o += (size_t)169 * 512 * 2;      // 173,056
    float* vbp = (float*)(ws + o);                   o += 1024;
    float* qp  = (float*)(ws + o);                   o += 1024;                        // 175,104
    unsigned short* Bc2 = (unsigned short*)(ws + o);
    float* a_buf = (float*)(ws + o);                 // alias of Bc2 (491,520 <= 768,000)
    o += (size_t)750 * 512 * 2;                      // -> 943,104
    unsigned short* Cws = (unsigned short*)(ws + o);

    const int NP = 750 * 512 + 169 * 512;            // 470,528
    kP<<<(NP + 255) / 256, 256, 0, stream>>>(conv_w, v, vb, q, Bc2, Bv2, vbp, qp);
    k1_conv<<<BB / 4, 640, 0, stream>>>(idx, emb, Bc2, conv_b, Cws);
    k2_att<<<(BB * NN) / 128, 256, 0, stream>>>(Cws, Bv2, vbp, qp, a_buf);
    k3_softmax<<<NN, 256, 0, stream>>>(a_buf, idx);
    k4_pool<<<BB, 128, 0, stream>>>(a_buf, Cws, out);
}